// Round 9
// baseline (321.923 us; speedup 1.0000x reference)
//
#include <hip/hip_runtime.h>
#include <cstdint>
#include <cstddef>

typedef unsigned short u16;
typedef short bf16x8 __attribute__((ext_vector_type(8)));
typedef unsigned short u16x4 __attribute__((ext_vector_type(4)));
typedef unsigned short u16x8 __attribute__((ext_vector_type(8)));
typedef float f32x4 __attribute__((ext_vector_type(4)));

#define EPSN 1e-12f

__device__ __forceinline__ u16 f2bf(float f) {
  uint32_t u = __builtin_bit_cast(uint32_t, f);
  u += 0x7FFFu + ((u >> 16) & 1u);
  return (u16)(u >> 16);
}
__device__ __forceinline__ float bf2f(u16 h) {
  uint32_t u = ((uint32_t)h) << 16;
  return __builtin_bit_cast(float, u);
}

__device__ __forceinline__ void gll16(const u16* g, u16* l) {
  __builtin_amdgcn_global_load_lds(
      (const __attribute__((address_space(1))) void*)g,
      (__attribute__((address_space(3))) void*)l, 16, 0, 0);
}

// ---------------------------------------------------------------------------
// x f32 -> Xh bf16 (row-major) + XhT bf16 (transposed), 64x64 tiles.
// ---------------------------------------------------------------------------
__global__ __launch_bounds__(256)
void k_cvtT(const float* __restrict__ x, u16* __restrict__ Xh,
            u16* __restrict__ XhT) {
  __shared__ u16 tr[64][68];  // [k][t]
  const int tid = threadIdx.x;
  const int t0 = blockIdx.x * 64, k0 = blockIdx.y * 64, b = blockIdx.z;
  const int rq = tid >> 4;
  const int cq = tid & 15;
  const size_t base = ((size_t)b * 4096 + t0) * 768 + k0;
  u16 m[4][4];
#pragma unroll
  for (int e = 0; e < 4; e++) {
    const int r = rq * 4 + e;
    f32x4 v = *(const f32x4*)(x + base + (size_t)r * 768 + cq * 4);
    u16x4 o;
#pragma unroll
    for (int q = 0; q < 4; q++) o[q] = f2bf(v[q]);
    *(u16x4*)(Xh + base + (size_t)r * 768 + cq * 4) = o;
    m[e][0] = o[0]; m[e][1] = o[1]; m[e][2] = o[2]; m[e][3] = o[3];
  }
#pragma unroll
  for (int q = 0; q < 4; q++) {
    u16x4 w;
    w[0] = m[0][q]; w[1] = m[1][q]; w[2] = m[2][q]; w[3] = m[3][q];
    *(u16x4*)&tr[cq * 4 + q][rq * 4] = w;
  }
  __syncthreads();
  const size_t tbase = ((size_t)b * 768 + k0) * 4096 + t0;
#pragma unroll
  for (int p = 0; p < 4; p++) {
    const int kk = (tid >> 4) + p * 16;
    const int ts = (tid & 15) * 4;
    u16x4 o = *(const u16x4*)&tr[kk][ts];
    *(u16x4*)(XhT + tbase + (size_t)kk * 4096 + ts) = o;
  }
}

// ---------------------------------------------------------------------------
// Wqkv: cols [0,1536) -> Wt transposed bf16; cols [1536,2304) -> Wvh row-major
// ---------------------------------------------------------------------------
__global__ __launch_bounds__(256)
void k_wt(const float* __restrict__ W, u16* __restrict__ Wt, u16* __restrict__ Wvh) {
  __shared__ float tile[32][33];
  const int j0 = blockIdx.x * 32;
  const int k0 = blockIdx.y * 32;
  const int tx = threadIdx.x & 31;
  const int ty = threadIdx.x >> 5;
#pragma unroll
  for (int r = 0; r < 4; r++) {
    float v = W[(size_t)(k0 + ty + r * 8) * 2304 + j0 + tx];
    tile[ty + r * 8][tx] = v;
    if (j0 >= 1536)
      Wvh[(size_t)(k0 + ty + r * 8) * 768 + (j0 - 1536) + tx] = f2bf(v);
  }
  __syncthreads();
  if (j0 < 1536) {
#pragma unroll
    for (int r = 0; r < 4; r++)
      Wt[(size_t)(j0 + ty + r * 8) * 768 + k0 + tx] = f2bf(tile[tx][ty + r * 8]);
  }
}

// ---------------------------------------------------------------------------
// Round-5 pipelined MFMA GEMM (128x128, 4 waves, 3-slot ring, counted vmcnt).
// Used for XtX (TRI=1), T, Wcomp. TRI: A==B Gram triangle, compact C tiles.
// ---------------------------------------------------------------------------
template <int OUTF32B, int TRI>
__global__ __launch_bounds__(256, 3)
void k_gemm(const u16* __restrict__ A, const u16* __restrict__ Btp,
            void* __restrict__ Cp, const float* __restrict__ bias,
            int K, int lda, int ldb, int ldc,
            long aZ, long bZ, long cZ, int zK, long kss) {
  const int gx = gridDim.x, gy = gridDim.y;
  int f = blockIdx.x + gx * (blockIdx.y + gy * blockIdx.z);
  const int total = gx * gy * gridDim.z;
  const int q = total >> 3, rr = total & 7;
  const int xcd = f & 7, kk0 = f >> 3;
  f = (xcd < rr ? xcd * (q + 1) : rr * (q + 1) + (xcd - rr) * q) + kk0;
  const int bx = f % gx;
  const int tmp = f / gx;
  const int by = tmp % gy;
  const int bz = tmp / gy;

  int m0, n0;
  if constexpr (TRI) {
    const int ty = (bx >= 20) ? 5 : (bx >= 18) ? 4 : (bx >= 15) ? 3
                 : (bx >= 11) ? 2 : (bx >= 6) ? 1 : 0;
    const int txi = ty + (bx - (ty * 6 - (ty * (ty - 1)) / 2));
    m0 = ty * 128;
    n0 = txi * 128;
  } else {
    m0 = by * 128;
    n0 = bx * 128;
  }
  const int z = bz;
  const int bb = z / zK, ss = z % zK;
  const u16* Az = A + (long)bb * aZ + (long)ss * kss;
  const u16* Btz = Btp + (long)bb * bZ + (long)ss * kss;

  __shared__ u16 As[3 * 128 * 32];
  __shared__ u16 Bs[3 * 128 * 32];
  const int tid = threadIdx.x;
  const int lane = tid & 63;
  const int wid = tid >> 6;
  const int wr = wid >> 1, wc = wid & 1;
  const int fm = lane & 15, kg = lane >> 4;

  const int lr = lane >> 2;
  const int gk = (lane & 3) ^ ((lane >> 3) & 3);
  const u16* gA = Az + (size_t)(m0 + wid * 32 + lr) * lda + gk * 8;
  const u16* gB = Btz + (size_t)(n0 + wid * 32 + lr) * ldb + gk * 8;
  const size_t a16 = (size_t)16 * lda, b16 = (size_t)16 * ldb;
  u16* lA = As + wid * 1024;
  u16* lB = Bs + wid * 1024;
  const int kq = (kg ^ ((fm >> 1) & 3)) * 8;

  auto STAGE = [&](int slot, int ko) {
    u16* la = lA + slot * 4096;
    u16* lb = lB + slot * 4096;
    gll16(gA + ko, la);
    gll16(gA + ko + a16, la + 512);
    gll16(gB + ko, lb);
    gll16(gB + ko + b16, lb + 512);
  };

  const int nt = K >> 5;
  STAGE(0, 0);
  STAGE(1, 32);
  int sC = 0, sN = 1, sS = 2;

  f32x4 acc[4][4] = {};
  for (int t = 0; t < nt; ++t) {
    if (t + 2 < nt) {
      STAGE(sS, (t + 2) * 32);
      __builtin_amdgcn_sched_barrier(0);
      asm volatile("s_waitcnt vmcnt(8)" ::: "memory");
    } else if (t + 2 == nt) {
      asm volatile("s_waitcnt vmcnt(4)" ::: "memory");
    } else {
      asm volatile("s_waitcnt vmcnt(0)" ::: "memory");
    }
    __builtin_amdgcn_sched_barrier(0);
    __builtin_amdgcn_s_barrier();
    __builtin_amdgcn_sched_barrier(0);

    const u16* as_ = As + sC * 4096;
    const u16* bs_ = Bs + sC * 4096;
    bf16x8 af[4], bfr[4];
#pragma unroll
    for (int i = 0; i < 4; i++)
      af[i] = *(const bf16x8*)&as_[(wr * 64 + i * 16 + fm) * 32 + kq];
#pragma unroll
    for (int j = 0; j < 4; j++)
      bfr[j] = *(const bf16x8*)&bs_[(wc * 64 + j * 16 + fm) * 32 + kq];
    asm volatile("s_waitcnt lgkmcnt(0)" ::: "memory");
    __builtin_amdgcn_sched_barrier(0);
    __builtin_amdgcn_s_barrier();
    __builtin_amdgcn_sched_barrier(0);

#pragma unroll
    for (int i = 0; i < 4; i++)
#pragma unroll
      for (int j = 0; j < 4; j++)
        acc[i][j] = __builtin_amdgcn_mfma_f32_16x16x32_bf16(af[i], bfr[j], acc[i][j], 0, 0, 0);

    const int t2 = sC; sC = sN; sN = sS; sS = t2;
  }

  if constexpr (OUTF32B) {
    float* C = (float*)Cp + (long)z * cZ;
#pragma unroll
    for (int j = 0; j < 4; j++) {
      const int col = n0 + wc * 64 + j * 16 + fm;
      const float bj = bias[col];
#pragma unroll
      for (int i = 0; i < 4; i++) {
        const int r0 = m0 + wr * 64 + i * 16 + kg * 4;
#pragma unroll
        for (int r = 0; r < 4; r++)
          C[(size_t)(r0 + r) * ldc + col] = acc[i][j][r] + bj;
      }
    }
  } else {
    const int rb = TRI ? 0 : m0;
    const int cb = TRI ? 0 : n0;
    const int ld = TRI ? 128 : ldc;
    u16* C = (u16*)Cp + (long)z * cZ + (TRI ? (long)bx * 16384 : 0L);
#pragma unroll
    for (int j = 0; j < 4; j++) {
      const int col = cb + wc * 64 + j * 16 + fm;
#pragma unroll
      for (int i = 0; i < 4; i++) {
        const int r0 = rb + wr * 64 + i * 16 + kg * 4;
#pragma unroll
        for (int r = 0; r < 4; r++)
          C[(size_t)(r0 + r) * ld + col] = f2bf(acc[i][j][r]);
      }
    }
  }
}

// ---------------------------------------------------------------------------
// NEW: 256x256 tile, 8 waves (512 thr), wave tile 128x64 (acc[8][4]), BK=32,
// 3-slot LDS ring with counted vmcnt (round-5-verified sync structure, same
// 4-loads-per-STAGE flight counts). 2x reuse per staged byte vs 128-wide
// tiles; ds_read:MFMA 12:32 vs 8:16. LDS 96KB -> 1 block/CU.
// ---------------------------------------------------------------------------
__global__ __launch_bounds__(512, 2)
void k_gemm8(const u16* __restrict__ A, const u16* __restrict__ Btp,
             float* __restrict__ C, const float* __restrict__ bias,
             int K, int lda, int ldb, int ldc,
             long aZ, long bZ, long cZ) {
  const int gx = gridDim.x, gy = gridDim.y;
  int f = blockIdx.x + gx * (blockIdx.y + gy * blockIdx.z);
  const int total = gx * gy * gridDim.z;
  const int q = total >> 3, rr = total & 7;
  const int xcd = f & 7, kk0 = f >> 3;
  f = (xcd < rr ? xcd * (q + 1) : rr * (q + 1) + (xcd - rr) * q) + kk0;
  const int bx = f % gx;
  const int tmp = f / gx;
  const int by = tmp % gy;
  const int bz = tmp / gy;

  const int m0 = by * 256, n0 = bx * 256;
  const u16* Az = A + (long)bz * aZ;
  const u16* Btz = Btp + (long)bz * bZ;

  __shared__ u16 As[3 * 256 * 32];   // 48 KB
  __shared__ u16 Bs[3 * 256 * 32];   // 48 KB
  const int tid = threadIdx.x;
  const int lane = tid & 63;
  const int wid = tid >> 6;           // 0..7
  const int wm = wid >> 2, wn = wid & 3;
  const int fm = lane & 15, kg = lane >> 4;

  const int lr = lane >> 2;
  const int gk = (lane & 3) ^ ((lane >> 3) & 3);
  // staging: wave w covers rows [w*32, w*32+32) of both 256-row tiles
  const u16* gA = Az + (size_t)(m0 + wid * 32 + lr) * lda + gk * 8;
  const u16* gB = Btz + (size_t)(n0 + wid * 32 + lr) * ldb + gk * 8;
  const size_t a16 = (size_t)16 * lda, b16 = (size_t)16 * ldb;
  u16* lA = As + wid * 1024;
  u16* lB = Bs + wid * 1024;
  const int kq = (kg ^ ((fm >> 1) & 3)) * 8;

  auto STAGE = [&](int slot, int ko) {
    u16* la = lA + slot * 8192;
    u16* lb = lB + slot * 8192;
    gll16(gA + ko, la);
    gll16(gA + ko + a16, la + 512);
    gll16(gB + ko, lb);
    gll16(gB + ko + b16, lb + 512);
  };

  const int nt = K >> 5;   // 24
  STAGE(0, 0);
  STAGE(1, 32);
  int sC = 0, sN = 1, sS = 2;

  f32x4 acc[8][4] = {};
  for (int t = 0; t < nt; ++t) {
    if (t + 2 < nt) {
      STAGE(sS, (t + 2) * 32);
      __builtin_amdgcn_sched_barrier(0);
      asm volatile("s_waitcnt vmcnt(8)" ::: "memory");   // tile t's 4 landed
    } else if (t + 2 == nt) {
      asm volatile("s_waitcnt vmcnt(4)" ::: "memory");
    } else {
      asm volatile("s_waitcnt vmcnt(0)" ::: "memory");
    }
    __builtin_amdgcn_sched_barrier(0);
    __builtin_amdgcn_s_barrier();
    __builtin_amdgcn_sched_barrier(0);

    const u16* as_ = As + sC * 8192;
    const u16* bs_ = Bs + sC * 8192;
    bf16x8 af[8], bfr[4];
#pragma unroll
    for (int i = 0; i < 8; i++)
      af[i] = *(const bf16x8*)&as_[(wm * 128 + i * 16 + fm) * 32 + kq];
#pragma unroll
    for (int j = 0; j < 4; j++)
      bfr[j] = *(const bf16x8*)&bs_[(wn * 64 + j * 16 + fm) * 32 + kq];
    asm volatile("s_waitcnt lgkmcnt(0)" ::: "memory");
    __builtin_amdgcn_sched_barrier(0);
    __builtin_amdgcn_s_barrier();
    __builtin_amdgcn_sched_barrier(0);

#pragma unroll
    for (int i = 0; i < 8; i++)
#pragma unroll
      for (int j = 0; j < 4; j++)
        acc[i][j] = __builtin_amdgcn_mfma_f32_16x16x32_bf16(af[i], bfr[j], acc[i][j], 0, 0, 0);

    const int t2 = sC; sC = sN; sN = sS; sS = t2;
  }

  float* Cz = C + (long)bz * cZ;
#pragma unroll
  for (int j = 0; j < 4; j++) {
    const int col = n0 + wn * 64 + j * 16 + fm;
    const float bj = bias[col];
#pragma unroll
    for (int i = 0; i < 8; i++) {
      const int r0 = m0 + wm * 128 + i * 16 + kg * 4;
#pragma unroll
      for (int r = 0; r < 4; r++)
        Cz[(size_t)(r0 + r) * ldc + col] = acc[i][j][r] + bj;
    }
  }
}

// ---------------------------------------------------------------------------
// Reduce 4 K-split triangle partials -> full square XtXbf (bf16), mirroring
// lower-triangle output tiles via LDS transpose. grid (36, 8).
// ---------------------------------------------------------------------------
__global__ __launch_bounds__(256)
void k_red(const u16* __restrict__ P, u16* __restrict__ O) {
  const int b = blockIdx.y;
  const int ti = blockIdx.x / 6, tj = blockIdx.x % 6;
  const bool mirror = ti > tj;
  const int a = mirror ? tj : ti;
  const int c2 = mirror ? ti : tj;
  const int src = a * 6 - (a * (a - 1)) / 2 + (c2 - a);
  __shared__ u16 lt[128 * 128];
  const int tid = threadIdx.x;
  const int r = tid >> 1;
  const int ch = (tid & 1) * 64;
  float acc[64] = {};
  for (int s = 0; s < 4; s++) {
    const u16* p = P + ((size_t)(b * 4 + s) * 344064 + (size_t)src * 16384);
    __syncthreads();
#pragma unroll
    for (int it = 0; it < 8; it++) {
      const int idx = (tid + it * 256) * 8;
      *(u16x8*)&lt[idx] = *(const u16x8*)(p + idx);
    }
    __syncthreads();
    if (!mirror) {
#pragma unroll
      for (int e = 0; e < 64; e++) acc[e] += bf2f(lt[r * 128 + ch + e]);
    } else {
#pragma unroll
      for (int e = 0; e < 64; e++) acc[e] += bf2f(lt[(ch + e) * 128 + r]);
    }
  }
  u16* o = O + (size_t)b * 589824 + (size_t)(ti * 128 + r) * 768 + tj * 128 + ch;
#pragma unroll
  for (int v8 = 0; v8 < 8; v8++) {
    u16x8 w;
#pragma unroll
    for (int e = 0; e < 8; e++) w[e] = f2bf(acc[v8 * 8 + e]);
    *(u16x8*)(o + v8 * 8) = w;
  }
}

// ---------------------------------------------------------------------------
// Per (b,h): G = T1 * WkT^T, norms as dots, softmax -> Aattn
// ---------------------------------------------------------------------------
__global__ __launch_bounds__(256)
void k_score(const u16* __restrict__ Tm, const u16* __restrict__ Wt,
             const float* __restrict__ temperature, float* __restrict__ Aattn) {
  const int h = blockIdx.x, b = blockIdx.y;
  const int bh = b * 8 + h;
  __shared__ u16 As[96 * 32];
  __shared__ u16 Bs[96 * 32];
  __shared__ u16 Dt2[96 * 32];
  __shared__ u16 Dwq[96 * 32];
  __shared__ float Gs[96 * 96];
  __shared__ float nqs[96], nks[96], invk[96];

  const int tid = threadIdx.x;
  const int lane = tid & 63;
  const int wid = tid >> 6;
  const int wr = wid >> 1, wc = wid & 1;
  const int fm = lane & 15, kg = lane >> 4;
  const int lr = lane >> 2;
  const int gkS = (lane & 3) ^ ((lane >> 3) & 3);
  const int gkL = (lane & 3);
  const int kq = (kg ^ ((fm >> 1) & 3)) * 8;

  const u16* baseT1 = Tm + (size_t)b * 1179648 + (size_t)(h * 96) * 768;
  const u16* baseT2 = baseT1 + (size_t)768 * 768;
  const u16* baseWq = Wt + (size_t)(h * 96) * 768;
  const u16* baseWk = baseWq + (size_t)768 * 768;

  const u16* gsrc;
  u16* ldst;
  int gblk = gkS;
  if (wid == 0) { gsrc = baseT1; ldst = As; }
  else if (wid == 1) { gsrc = baseWk; ldst = Bs; }
  else if (wid == 2) { gsrc = baseT2; ldst = Dt2; gblk = gkL; }
  else { gsrc = baseWq; ldst = Dwq; gblk = gkL; }

  f32x4 acc[3][3] = {};
  float nqa = 0.f, nka = 0.f;
  const int sw1 = (tid < 96) ? ((tid >> 1) & 3) : 0;
  const int sw2 = (tid >= 128 && tid < 224) ? (((tid - 128) >> 1) & 3) : 0;

  for (int k0 = 0; k0 < 768; k0 += 32) {
    __syncthreads();
#pragma unroll
    for (int c = 0; c < 6; c++) {
      gll16(gsrc + (size_t)(c * 16 + lr) * 768 + k0 + gblk * 8,
            ldst + c * 512);
    }
    __syncthreads();
    bf16x8 af[3], bfr[3];
#pragma unroll
    for (int i = 0; i < 3; i++)
      af[i] = *(const bf16x8*)&As[(wr * 48 + i * 16 + fm) * 32 + kq];
#pragma unroll
    for (int j = 0; j < 3; j++)
      bfr[j] = *(const bf16x8*)&Bs[(wc * 48 + j * 16 + fm) * 32 + kq];
#pragma unroll
    for (int i = 0; i < 3; i++)
#pragma unroll
      for (int j = 0; j < 3; j++)
        acc[i][j] = __builtin_amdgcn_mfma_f32_16x16x32_bf16(af[i], bfr[j], acc[i][j], 0, 0, 0);
    if (tid < 96) {
#pragma unroll
      for (int g = 0; g < 4; g++) {
        u16x8 av = *(const u16x8*)&As[tid * 32 + (g ^ sw1) * 8];
        u16x8 w = *(const u16x8*)&Dwq[tid * 32 + g * 8];
#pragma unroll
        for (int e = 0; e < 8; e++) nqa += bf2f(av[e]) * bf2f(w[e]);
      }
    } else if (tid >= 128 && tid < 224) {
      const int d = tid - 128;
#pragma unroll
      for (int g = 0; g < 4; g++) {
        u16x8 av = *(const u16x8*)&Bs[d * 32 + (g ^ sw2) * 8];
        u16x8 w = *(const u16x8*)&Dt2[d * 32 + g * 8];
#pragma unroll
        for (int e = 0; e < 8; e++) nka += bf2f(av[e]) * bf2f(w[e]);
      }
    }
  }

  if (tid < 96) nqs[tid] = nqa;
  if (tid >= 128 && tid < 224) nks[tid - 128] = nka;
#pragma unroll
  for (int i = 0; i < 3; i++)
#pragma unroll
    for (int j = 0; j < 3; j++)
#pragma unroll
      for (int r = 0; r < 4; r++)
        Gs[(wr * 48 + i * 16 + kg * 4 + r) * 96 + wc * 48 + j * 16 + fm] = acc[i][j][r];
  __syncthreads();
  if (tid < 96) invk[tid] = 1.0f / fmaxf(sqrtf(nks[tid]), EPSN);
  __syncthreads();
  if (tid < 96) {
    const int c = tid;
    const float iq = temperature[h] / fmaxf(sqrtf(nqs[c]), EPSN);
    float sv[96];
    float m = -1e30f;
#pragma unroll
    for (int d = 0; d < 96; d++) {
      float s = Gs[c * 96 + d] * iq * invk[d];
      sv[d] = s;
      m = fmaxf(m, s);
    }
    float sum = 0.f;
#pragma unroll
    for (int d = 0; d < 96; d++) {
      float e = __expf(sv[d] - m);
      sv[d] = e;
      sum += e;
    }
    const float inv = 1.0f / sum;
    float* dst = Aattn + (size_t)bh * 9216 + (size_t)c * 96;
#pragma unroll
    for (int d = 0; d < 96; d++) dst[d] = sv[d] * inv;
  }
}

// ---------------------------------------------------------------------------
// WeffT[b][j][e] = sum_c A[b,h(e),c,dc(e)] * Wproj[h*96+c][j]   (bf16 out)
// ---------------------------------------------------------------------------
__global__ __launch_bounds__(256)
void k_weff(const float* __restrict__ Aattn, const float* __restrict__ Wproj,
            u16* __restrict__ Weff) {
  const int jt = blockIdx.x, h = blockIdx.y, b = blockIdx.z;
  const int bh = b * 8 + h;
  __shared__ float As2[9216];
  const int tid = threadIdx.x;
  for (int idx = tid; idx < 9216; idx += 256)
    As2[idx] = Aattn[(size_t)bh * 9216 + idx];
  __syncthreads();
  const int jloc = tid & 127;
  const int half = tid >> 7;
  const int j = jt * 128 + jloc;
  float acc[48] = {};
  for (int c = 0; c < 96; c++) {
    const float w = Wproj[(size_t)(h * 96 + c) * 768 + j];
    const f32x4* ar = (const f32x4*)&As2[c * 96 + half * 48];
#pragma unroll
    for (int v4 = 0; v4 < 12; v4++) {
      f32x4 av = ar[v4];
      acc[v4 * 4 + 0] += w * av[0];
      acc[v4 * 4 + 1] += w * av[1];
      acc[v4 * 4 + 2] += w * av[2];
      acc[v4 * 4 + 3] += w * av[3];
    }
  }
  u16* dst = Weff + ((size_t)b * 768 + j) * 768 + h * 96 + half * 48;
#pragma unroll
  for (int v4 = 0; v4 < 12; v4++) {
    u16x4 o;
    o[0] = f2bf(acc[v4 * 4 + 0]);
    o[1] = f2bf(acc[v4 * 4 + 1]);
    o[2] = f2bf(acc[v4 * 4 + 2]);
    o[3] = f2bf(acc[v4 * 4 + 3]);
    *(u16x4*)(dst + v4 * 4) = o;
  }
}

// ---------------------------------------------------------------------------
extern "C" void kernel_launch(void* const* d_in, const int* in_sizes, int n_in,
                              void* d_out, int out_size, void* d_ws, size_t ws_size,
                              hipStream_t stream) {
  const float* x = (const float*)d_in[0];
  const float* Wqkv = (const float*)d_in[1];
  const float* temp = (const float*)d_in[2];
  const float* Wproj = (const float*)d_in[3];
  const float* bproj = (const float*)d_in[4];
  float* out = (float*)d_out;

  char* ws = (char*)d_ws;
  u16* Xh = (u16*)ws;                       // 50,331,648 B
  u16* XhT = (u16*)(ws + 50331648);         // 50,331,648 B
  u16* Wt = (u16*)(ws + 100663296);         // 2,359,296 B
  u16* Wvh = (u16*)(ws + 103022592);        // 1,179,648 B
  u16* XtXp = (u16*)(ws + 104202240);       // 32 z x 21 tiles x 16384 bf16
  u16* XtXbf = (u16*)(ws + 141950976);      // 8 x 589824 bf16
  u16* T = (u16*)(ws + 151388160);          // 8 x 1536 x 768 bf16
  u16* WeffT = (u16*)(ws + 151388160);      // alias: T dead after k_score
  u16* WcompT = (u16*)(ws + 160825344);
  float* Aattn = (float*)(ws + 170262528);  // 64 x 9216 f32
  // total ws use: 172,621,824 B

  // 1. x -> Xh + XhT
  k_cvtT<<<dim3(64, 12, 8), 256, 0, stream>>>(x, Xh, XhT);
  // 2. Wqkv -> Wt + Wvh
  k_wt<<<dim3(72, 24), 256, 0, stream>>>(Wqkv, Wt, Wvh);
  // 3. XtX triangle partials: per (b,s), 21 tile-pairs
  k_gemm<0, 1><<<dim3(21, 1, 32), 256, 0, stream>>>(
      XhT, XhT, (void*)XtXp, nullptr, 1024, 4096, 4096, 0,
      3145728L, 3145728L, 344064L, 4, 1024L);
  // 4. reduce + mirror -> XtXbf (full square)
  k_red<<<dim3(36, 8), 256, 0, stream>>>(XtXp, XtXbf);
  // 5. T[b] = Wt @ XtXbf_b (symmetric -> Bt=XtX)
  k_gemm<0, 0><<<dim3(6, 12, 8), 256, 0, stream>>>(
      Wt, XtXbf, (void*)T, nullptr, 768, 768, 768, 768,
      0L, 589824L, 1179648L, 1, 0L);
  // 6. scores + softmax -> Aattn
  k_score<<<dim3(8, 8), 256, 0, stream>>>(T, Wt, temp, Aattn);
  // 7. WeffT = blockdiag(A)^T @ Wproj
  k_weff<<<dim3(6, 8, 8), 256, 0, stream>>>(Aattn, Wproj, WeffT);
  // 8. WcompT[b][j][k] = sum_e WeffT[b][j][e] * Wvh[k][e]
  k_gemm<0, 0><<<dim3(6, 6, 8), 256, 0, stream>>>(
      WeffT, Wvh, (void*)WcompT, nullptr, 768, 768, 768, 768,
      589824L, 0L, 589824L, 1, 0L);
  // 9. out = Xh_b @ Wcomp_b + bproj (f32 out) -- NEW 256x256 8-wave kernel
  k_gemm8<<<dim3(3, 16, 8), 512, 0, stream>>>(
      Xh, WcompT, out, bproj, 768, 768, 768, 768,
      3145728L, 589824L, 3145728L);
}

// Round 10
// 296.931 us; speedup vs baseline: 1.0842x; 1.0842x over previous
//
#include <hip/hip_runtime.h>
#include <cstdint>
#include <cstddef>

typedef unsigned short u16;
typedef short bf16x8 __attribute__((ext_vector_type(8)));
typedef unsigned short u16x4 __attribute__((ext_vector_type(4)));
typedef unsigned short u16x8 __attribute__((ext_vector_type(8)));
typedef float f32x4 __attribute__((ext_vector_type(4)));

#define EPSN 1e-12f

__device__ __forceinline__ u16 f2bf(float f) {
  uint32_t u = __builtin_bit_cast(uint32_t, f);
  u += 0x7FFFu + ((u >> 16) & 1u);
  return (u16)(u >> 16);
}
__device__ __forceinline__ float bf2f(u16 h) {
  uint32_t u = ((uint32_t)h) << 16;
  return __builtin_bit_cast(float, u);
}

__device__ __forceinline__ void gll16(const u16* g, u16* l) {
  __builtin_amdgcn_global_load_lds(
      (const __attribute__((address_space(1))) void*)g,
      (__attribute__((address_space(3))) void*)l, 16, 0, 0);
}

// ---------------------------------------------------------------------------
// x f32 -> Xh bf16 (row-major) + XhT bf16 (transposed), 64x64 tiles.
// ---------------------------------------------------------------------------
__global__ __launch_bounds__(256)
void k_cvtT(const float* __restrict__ x, u16* __restrict__ Xh,
            u16* __restrict__ XhT) {
  __shared__ u16 tr[64][68];  // [k][t]
  const int tid = threadIdx.x;
  const int t0 = blockIdx.x * 64, k0 = blockIdx.y * 64, b = blockIdx.z;
  const int rq = tid >> 4;
  const int cq = tid & 15;
  const size_t base = ((size_t)b * 4096 + t0) * 768 + k0;
  u16 m[4][4];
#pragma unroll
  for (int e = 0; e < 4; e++) {
    const int r = rq * 4 + e;
    f32x4 v = *(const f32x4*)(x + base + (size_t)r * 768 + cq * 4);
    u16x4 o;
#pragma unroll
    for (int q = 0; q < 4; q++) o[q] = f2bf(v[q]);
    *(u16x4*)(Xh + base + (size_t)r * 768 + cq * 4) = o;
    m[e][0] = o[0]; m[e][1] = o[1]; m[e][2] = o[2]; m[e][3] = o[3];
  }
#pragma unroll
  for (int q = 0; q < 4; q++) {
    u16x4 w;
    w[0] = m[0][q]; w[1] = m[1][q]; w[2] = m[2][q]; w[3] = m[3][q];
    *(u16x4*)&tr[cq * 4 + q][rq * 4] = w;
  }
  __syncthreads();
  const size_t tbase = ((size_t)b * 768 + k0) * 4096 + t0;
#pragma unroll
  for (int p = 0; p < 4; p++) {
    const int kk = (tid >> 4) + p * 16;
    const int ts = (tid & 15) * 4;
    u16x4 o = *(const u16x4*)&tr[kk][ts];
    *(u16x4*)(XhT + tbase + (size_t)kk * 4096 + ts) = o;
  }
}

// ---------------------------------------------------------------------------
// Wqkv: cols [0,1536) -> Wt transposed bf16; cols [1536,2304) -> Wvh row-major
// ---------------------------------------------------------------------------
__global__ __launch_bounds__(256)
void k_wt(const float* __restrict__ W, u16* __restrict__ Wt, u16* __restrict__ Wvh) {
  __shared__ float tile[32][33];
  const int j0 = blockIdx.x * 32;
  const int k0 = blockIdx.y * 32;
  const int tx = threadIdx.x & 31;
  const int ty = threadIdx.x >> 5;
#pragma unroll
  for (int r = 0; r < 4; r++) {
    float v = W[(size_t)(k0 + ty + r * 8) * 2304 + j0 + tx];
    tile[ty + r * 8][tx] = v;
    if (j0 >= 1536)
      Wvh[(size_t)(k0 + ty + r * 8) * 768 + (j0 - 1536) + tx] = f2bf(v);
  }
  __syncthreads();
  if (j0 < 1536) {
#pragma unroll
    for (int r = 0; r < 4; r++)
      Wt[(size_t)(j0 + ty + r * 8) * 768 + k0 + tx] = f2bf(tile[tx][ty + r * 8]);
  }
}

// ---------------------------------------------------------------------------
// Round-5 pipelined MFMA GEMM (128x128, 4 waves, 3-slot ring, counted vmcnt).
// Used for XtX (TRI=1), T, Wcomp. TRI: A==B Gram triangle, compact C tiles.
// ---------------------------------------------------------------------------
template <int OUTF32B, int TRI>
__global__ __launch_bounds__(256, 3)
void k_gemm(const u16* __restrict__ A, const u16* __restrict__ Btp,
            void* __restrict__ Cp, const float* __restrict__ bias,
            int K, int lda, int ldb, int ldc,
            long aZ, long bZ, long cZ, int zK, long kss) {
  const int gx = gridDim.x, gy = gridDim.y;
  int f = blockIdx.x + gx * (blockIdx.y + gy * blockIdx.z);
  const int total = gx * gy * gridDim.z;
  const int q = total >> 3, rr = total & 7;
  const int xcd = f & 7, kk0 = f >> 3;
  f = (xcd < rr ? xcd * (q + 1) : rr * (q + 1) + (xcd - rr) * q) + kk0;
  const int bx = f % gx;
  const int tmp = f / gx;
  const int by = tmp % gy;
  const int bz = tmp / gy;

  int m0, n0;
  if constexpr (TRI) {
    const int ty = (bx >= 20) ? 5 : (bx >= 18) ? 4 : (bx >= 15) ? 3
                 : (bx >= 11) ? 2 : (bx >= 6) ? 1 : 0;
    const int txi = ty + (bx - (ty * 6 - (ty * (ty - 1)) / 2));
    m0 = ty * 128;
    n0 = txi * 128;
  } else {
    m0 = by * 128;
    n0 = bx * 128;
  }
  const int z = bz;
  const int bb = z / zK, ss = z % zK;
  const u16* Az = A + (long)bb * aZ + (long)ss * kss;
  const u16* Btz = Btp + (long)bb * bZ + (long)ss * kss;

  __shared__ u16 As[3 * 128 * 32];
  __shared__ u16 Bs[3 * 128 * 32];
  const int tid = threadIdx.x;
  const int lane = tid & 63;
  const int wid = tid >> 6;
  const int wr = wid >> 1, wc = wid & 1;
  const int fm = lane & 15, kg = lane >> 4;

  const int lr = lane >> 2;
  const int gk = (lane & 3) ^ ((lane >> 3) & 3);
  const u16* gA = Az + (size_t)(m0 + wid * 32 + lr) * lda + gk * 8;
  const u16* gB = Btz + (size_t)(n0 + wid * 32 + lr) * ldb + gk * 8;
  const size_t a16 = (size_t)16 * lda, b16 = (size_t)16 * ldb;
  u16* lA = As + wid * 1024;
  u16* lB = Bs + wid * 1024;
  const int kq = (kg ^ ((fm >> 1) & 3)) * 8;

  auto STAGE = [&](int slot, int ko) {
    u16* la = lA + slot * 4096;
    u16* lb = lB + slot * 4096;
    gll16(gA + ko, la);
    gll16(gA + ko + a16, la + 512);
    gll16(gB + ko, lb);
    gll16(gB + ko + b16, lb + 512);
  };

  const int nt = K >> 5;
  STAGE(0, 0);
  STAGE(1, 32);
  int sC = 0, sN = 1, sS = 2;

  f32x4 acc[4][4] = {};
  for (int t = 0; t < nt; ++t) {
    if (t + 2 < nt) {
      STAGE(sS, (t + 2) * 32);
      __builtin_amdgcn_sched_barrier(0);
      asm volatile("s_waitcnt vmcnt(8)" ::: "memory");
    } else if (t + 2 == nt) {
      asm volatile("s_waitcnt vmcnt(4)" ::: "memory");
    } else {
      asm volatile("s_waitcnt vmcnt(0)" ::: "memory");
    }
    __builtin_amdgcn_sched_barrier(0);
    __builtin_amdgcn_s_barrier();
    __builtin_amdgcn_sched_barrier(0);

    const u16* as_ = As + sC * 4096;
    const u16* bs_ = Bs + sC * 4096;
    bf16x8 af[4], bfr[4];
#pragma unroll
    for (int i = 0; i < 4; i++)
      af[i] = *(const bf16x8*)&as_[(wr * 64 + i * 16 + fm) * 32 + kq];
#pragma unroll
    for (int j = 0; j < 4; j++)
      bfr[j] = *(const bf16x8*)&bs_[(wc * 64 + j * 16 + fm) * 32 + kq];
    asm volatile("s_waitcnt lgkmcnt(0)" ::: "memory");
    __builtin_amdgcn_sched_barrier(0);
    __builtin_amdgcn_s_barrier();
    __builtin_amdgcn_sched_barrier(0);

#pragma unroll
    for (int i = 0; i < 4; i++)
#pragma unroll
      for (int j = 0; j < 4; j++)
        acc[i][j] = __builtin_amdgcn_mfma_f32_16x16x32_bf16(af[i], bfr[j], acc[i][j], 0, 0, 0);

    const int t2 = sC; sC = sN; sN = sS; sS = t2;
  }

  if constexpr (OUTF32B) {
    float* C = (float*)Cp + (long)z * cZ;
#pragma unroll
    for (int j = 0; j < 4; j++) {
      const int col = n0 + wc * 64 + j * 16 + fm;
      const float bj = bias[col];
#pragma unroll
      for (int i = 0; i < 4; i++) {
        const int r0 = m0 + wr * 64 + i * 16 + kg * 4;
#pragma unroll
        for (int r = 0; r < 4; r++)
          C[(size_t)(r0 + r) * ldc + col] = acc[i][j][r] + bj;
      }
    }
  } else {
    const int rb = TRI ? 0 : m0;
    const int cb = TRI ? 0 : n0;
    const int ld = TRI ? 128 : ldc;
    u16* C = (u16*)Cp + (long)z * cZ + (TRI ? (long)bx * 16384 : 0L);
#pragma unroll
    for (int j = 0; j < 4; j++) {
      const int col = cb + wc * 64 + j * 16 + fm;
#pragma unroll
      for (int i = 0; i < 4; i++) {
        const int r0 = rb + wr * 64 + i * 16 + kg * 4;
#pragma unroll
        for (int r = 0; r < 4; r++)
          C[(size_t)(r0 + r) * ld + col] = f2bf(acc[i][j][r]);
      }
    }
  }
}

// ---------------------------------------------------------------------------
// 256x128 8-wave GEMM (wave tile 64x64, 2x LDS double-buffer, one
// __syncthreads per K-iter). Best measured config for the out-GEMM (step 9).
// ---------------------------------------------------------------------------
template <int OUTF32B>
__global__ __launch_bounds__(512, 4)
void k_gemm2(const u16* __restrict__ A, const u16* __restrict__ Btp,
             void* __restrict__ Cp, const float* __restrict__ bias,
             int K, int lda, int ldb, int ldc,
             long aZ, long bZ, long cZ) {
  const int gx = gridDim.x, gy = gridDim.y;
  int f = blockIdx.x + gx * (blockIdx.y + gy * blockIdx.z);
  const int total = gx * gy * gridDim.z;
  const int q = total >> 3, rr = total & 7;
  const int xcd = f & 7, kk0 = f >> 3;
  f = (xcd < rr ? xcd * (q + 1) : rr * (q + 1) + (xcd - rr) * q) + kk0;
  const int bx = f % gx;
  const int tmp = f / gx;
  const int by = tmp % gy;
  const int bz = tmp / gy;

  const int m0 = by * 256, n0 = bx * 128;
  const u16* Az = A + (long)bz * aZ;
  const u16* Btz = Btp + (long)bz * bZ;

  __shared__ u16 As[2][256 * 32];   // 16KB/slot
  __shared__ u16 Bs[2][128 * 32];   // 8KB/slot
  const int tid = threadIdx.x;
  const int lane = tid & 63;
  const int wid = tid >> 6;          // 0..7
  const int wr = wid & 3, wc = wid >> 2;
  const int fm = lane & 15, kg = lane >> 4;

  const int lr = lane >> 2;
  const int gk = (lane & 3) ^ ((lane >> 3) & 3);
  // staging: wave w -> A rows [w*32, w*32+32), B rows [w*16, w*16+16)
  const u16* gA = Az + (size_t)(m0 + wid * 32 + lr) * lda + gk * 8;
  const u16* gB = Btz + (size_t)(n0 + wid * 16 + lr) * ldb + gk * 8;
  const size_t a16 = (size_t)16 * lda;
  const int kq = (kg ^ ((fm >> 1) & 3)) * 8;

  auto STAGE = [&](int s, int ko) {
    u16* la = &As[s][wid * 1024];
    u16* lb = &Bs[s][wid * 512];
    gll16(gA + ko, la);
    gll16(gA + ko + a16, la + 512);
    gll16(gB + ko, lb);
  };

  const int nt = K >> 5;
  STAGE(0, 0);
  int cur = 0;

  f32x4 acc[4][4] = {};
  for (int t = 0; t < nt; ++t) {
    __syncthreads();                 // drains own stage loads; syncs reads
    bf16x8 af[4], bfr[4];
#pragma unroll
    for (int i = 0; i < 4; i++)
      af[i] = *(const bf16x8*)&As[cur][(wr * 64 + i * 16 + fm) * 32 + kq];
#pragma unroll
    for (int j = 0; j < 4; j++)
      bfr[j] = *(const bf16x8*)&Bs[cur][(wc * 64 + j * 16 + fm) * 32 + kq];
    if (t + 1 < nt) STAGE(cur ^ 1, (t + 1) * 32);
#pragma unroll
    for (int i = 0; i < 4; i++)
#pragma unroll
      for (int j = 0; j < 4; j++)
        acc[i][j] = __builtin_amdgcn_mfma_f32_16x16x32_bf16(af[i], bfr[j], acc[i][j], 0, 0, 0);
    cur ^= 1;
  }

  if constexpr (OUTF32B) {
    float* C = (float*)Cp + (long)bz * cZ;
#pragma unroll
    for (int j = 0; j < 4; j++) {
      const int col = n0 + wc * 64 + j * 16 + fm;
      const float bj = bias[col];
#pragma unroll
      for (int i = 0; i < 4; i++) {
        const int r0 = m0 + wr * 64 + i * 16 + kg * 4;
#pragma unroll
        for (int r = 0; r < 4; r++)
          C[(size_t)(r0 + r) * ldc + col] = acc[i][j][r] + bj;
      }
    }
  } else {
    u16* C = (u16*)Cp + (long)bz * cZ;
#pragma unroll
    for (int j = 0; j < 4; j++) {
      const int col = n0 + wc * 64 + j * 16 + fm;
#pragma unroll
      for (int i = 0; i < 4; i++) {
        const int r0 = m0 + wr * 64 + i * 16 + kg * 4;
#pragma unroll
        for (int r = 0; r < 4; r++)
          C[(size_t)(r0 + r) * ldc + col] = f2bf(acc[i][j][r]);
      }
    }
  }
}

// ---------------------------------------------------------------------------
// Reduce 4 K-split triangle partials -> full square XtXbf (bf16), mirroring
// lower-triangle output tiles via LDS transpose. grid (36, 8).
// ---------------------------------------------------------------------------
__global__ __launch_bounds__(256)
void k_red(const u16* __restrict__ P, u16* __restrict__ O) {
  const int b = blockIdx.y;
  const int ti = blockIdx.x / 6, tj = blockIdx.x % 6;
  const bool mirror = ti > tj;
  const int a = mirror ? tj : ti;
  const int c2 = mirror ? ti : tj;
  const int src = a * 6 - (a * (a - 1)) / 2 + (c2 - a);
  __shared__ u16 lt[128 * 128];
  const int tid = threadIdx.x;
  const int r = tid >> 1;
  const int ch = (tid & 1) * 64;
  float acc[64] = {};
  for (int s = 0; s < 4; s++) {
    const u16* p = P + ((size_t)(b * 4 + s) * 344064 + (size_t)src * 16384);
    __syncthreads();
#pragma unroll
    for (int it = 0; it < 8; it++) {
      const int idx = (tid + it * 256) * 8;
      *(u16x8*)&lt[idx] = *(const u16x8*)(p + idx);
    }
    __syncthreads();
    if (!mirror) {
#pragma unroll
      for (int e = 0; e < 64; e++) acc[e] += bf2f(lt[r * 128 + ch + e]);
    } else {
#pragma unroll
      for (int e = 0; e < 64; e++) acc[e] += bf2f(lt[(ch + e) * 128 + r]);
    }
  }
  u16* o = O + (size_t)b * 589824 + (size_t)(ti * 128 + r) * 768 + tj * 128 + ch;
#pragma unroll
  for (int v8 = 0; v8 < 8; v8++) {
    u16x8 w;
#pragma unroll
    for (int e = 0; e < 8; e++) w[e] = f2bf(acc[v8 * 8 + e]);
    *(u16x8*)(o + v8 * 8) = w;
  }
}

// ---------------------------------------------------------------------------
// Per (b,h): G = T1 * WkT^T, norms as dots, softmax -> Aattn
// ---------------------------------------------------------------------------
__global__ __launch_bounds__(256)
void k_score(const u16* __restrict__ Tm, const u16* __restrict__ Wt,
             const float* __restrict__ temperature, float* __restrict__ Aattn) {
  const int h = blockIdx.x, b = blockIdx.y;
  const int bh = b * 8 + h;
  __shared__ u16 As[96 * 32];
  __shared__ u16 Bs[96 * 32];
  __shared__ u16 Dt2[96 * 32];
  __shared__ u16 Dwq[96 * 32];
  __shared__ float Gs[96 * 96];
  __shared__ float nqs[96], nks[96], invk[96];

  const int tid = threadIdx.x;
  const int lane = tid & 63;
  const int wid = tid >> 6;
  const int wr = wid >> 1, wc = wid & 1;
  const int fm = lane & 15, kg = lane >> 4;
  const int lr = lane >> 2;
  const int gkS = (lane & 3) ^ ((lane >> 3) & 3);
  const int gkL = (lane & 3);
  const int kq = (kg ^ ((fm >> 1) & 3)) * 8;

  const u16* baseT1 = Tm + (size_t)b * 1179648 + (size_t)(h * 96) * 768;
  const u16* baseT2 = baseT1 + (size_t)768 * 768;
  const u16* baseWq = Wt + (size_t)(h * 96) * 768;
  const u16* baseWk = baseWq + (size_t)768 * 768;

  const u16* gsrc;
  u16* ldst;
  int gblk = gkS;
  if (wid == 0) { gsrc = baseT1; ldst = As; }
  else if (wid == 1) { gsrc = baseWk; ldst = Bs; }
  else if (wid == 2) { gsrc = baseT2; ldst = Dt2; gblk = gkL; }
  else { gsrc = baseWq; ldst = Dwq; gblk = gkL; }

  f32x4 acc[3][3] = {};
  float nqa = 0.f, nka = 0.f;
  const int sw1 = (tid < 96) ? ((tid >> 1) & 3) : 0;
  const int sw2 = (tid >= 128 && tid < 224) ? (((tid - 128) >> 1) & 3) : 0;

  for (int k0 = 0; k0 < 768; k0 += 32) {
    __syncthreads();
#pragma unroll
    for (int c = 0; c < 6; c++) {
      gll16(gsrc + (size_t)(c * 16 + lr) * 768 + k0 + gblk * 8,
            ldst + c * 512);
    }
    __syncthreads();
    bf16x8 af[3], bfr[3];
#pragma unroll
    for (int i = 0; i < 3; i++)
      af[i] = *(const bf16x8*)&As[(wr * 48 + i * 16 + fm) * 32 + kq];
#pragma unroll
    for (int j = 0; j < 3; j++)
      bfr[j] = *(const bf16x8*)&Bs[(wc * 48 + j * 16 + fm) * 32 + kq];
#pragma unroll
    for (int i = 0; i < 3; i++)
#pragma unroll
      for (int j = 0; j < 3; j++)
        acc[i][j] = __builtin_amdgcn_mfma_f32_16x16x32_bf16(af[i], bfr[j], acc[i][j], 0, 0, 0);
    if (tid < 96) {
#pragma unroll
      for (int g = 0; g < 4; g++) {
        u16x8 av = *(const u16x8*)&As[tid * 32 + (g ^ sw1) * 8];
        u16x8 w = *(const u16x8*)&Dwq[tid * 32 + g * 8];
#pragma unroll
        for (int e = 0; e < 8; e++) nqa += bf2f(av[e]) * bf2f(w[e]);
      }
    } else if (tid >= 128 && tid < 224) {
      const int d = tid - 128;
#pragma unroll
      for (int g = 0; g < 4; g++) {
        u16x8 av = *(const u16x8*)&Bs[d * 32 + (g ^ sw2) * 8];
        u16x8 w = *(const u16x8*)&Dt2[d * 32 + g * 8];
#pragma unroll
        for (int e = 0; e < 8; e++) nka += bf2f(av[e]) * bf2f(w[e]);
      }
    }
  }

  if (tid < 96) nqs[tid] = nqa;
  if (tid >= 128 && tid < 224) nks[tid - 128] = nka;
#pragma unroll
  for (int i = 0; i < 3; i++)
#pragma unroll
    for (int j = 0; j < 3; j++)
#pragma unroll
      for (int r = 0; r < 4; r++)
        Gs[(wr * 48 + i * 16 + kg * 4 + r) * 96 + wc * 48 + j * 16 + fm] = acc[i][j][r];
  __syncthreads();
  if (tid < 96) invk[tid] = 1.0f / fmaxf(sqrtf(nks[tid]), EPSN);
  __syncthreads();
  if (tid < 96) {
    const int c = tid;
    const float iq = temperature[h] / fmaxf(sqrtf(nqs[c]), EPSN);
    float sv[96];
    float m = -1e30f;
#pragma unroll
    for (int d = 0; d < 96; d++) {
      float s = Gs[c * 96 + d] * iq * invk[d];
      sv[d] = s;
      m = fmaxf(m, s);
    }
    float sum = 0.f;
#pragma unroll
    for (int d = 0; d < 96; d++) {
      float e = __expf(sv[d] - m);
      sv[d] = e;
      sum += e;
    }
    const float inv = 1.0f / sum;
    float* dst = Aattn + (size_t)bh * 9216 + (size_t)c * 96;
#pragma unroll
    for (int d = 0; d < 96; d++) dst[d] = sv[d] * inv;
  }
}

// ---------------------------------------------------------------------------
// WeffT[b][j][e] = sum_c A[b,h(e),c,dc(e)] * Wproj[h*96+c][j]   (bf16 out)
// ---------------------------------------------------------------------------
__global__ __launch_bounds__(256)
void k_weff(const float* __restrict__ Aattn, const float* __restrict__ Wproj,
            u16* __restrict__ Weff) {
  const int jt = blockIdx.x, h = blockIdx.y, b = blockIdx.z;
  const int bh = b * 8 + h;
  __shared__ float As2[9216];
  const int tid = threadIdx.x;
  for (int idx = tid; idx < 9216; idx += 256)
    As2[idx] = Aattn[(size_t)bh * 9216 + idx];
  __syncthreads();
  const int jloc = tid & 127;
  const int half = tid >> 7;
  const int j = jt * 128 + jloc;
  float acc[48] = {};
  for (int c = 0; c < 96; c++) {
    const float w = Wproj[(size_t)(h * 96 + c) * 768 + j];
    const f32x4* ar = (const f32x4*)&As2[c * 96 + half * 48];
#pragma unroll
    for (int v4 = 0; v4 < 12; v4++) {
      f32x4 av = ar[v4];
      acc[v4 * 4 + 0] += w * av[0];
      acc[v4 * 4 + 1] += w * av[1];
      acc[v4 * 4 + 2] += w * av[2];
      acc[v4 * 4 + 3] += w * av[3];
    }
  }
  u16* dst = Weff + ((size_t)b * 768 + j) * 768 + h * 96 + half * 48;
#pragma unroll
  for (int v4 = 0; v4 < 12; v4++) {
    u16x4 o;
    o[0] = f2bf(acc[v4 * 4 + 0]);
    o[1] = f2bf(acc[v4 * 4 + 1]);
    o[2] = f2bf(acc[v4 * 4 + 2]);
    o[3] = f2bf(acc[v4 * 4 + 3]);
    *(u16x4*)(dst + v4 * 4) = o;
  }
}

// ---------------------------------------------------------------------------
extern "C" void kernel_launch(void* const* d_in, const int* in_sizes, int n_in,
                              void* d_out, int out_size, void* d_ws, size_t ws_size,
                              hipStream_t stream) {
  const float* x = (const float*)d_in[0];
  const float* Wqkv = (const float*)d_in[1];
  const float* temp = (const float*)d_in[2];
  const float* Wproj = (const float*)d_in[3];
  const float* bproj = (const float*)d_in[4];
  float* out = (float*)d_out;

  char* ws = (char*)d_ws;
  u16* Xh = (u16*)ws;                       // 50,331,648 B
  u16* XhT = (u16*)(ws + 50331648);         // 50,331,648 B
  u16* Wt = (u16*)(ws + 100663296);         // 2,359,296 B
  u16* Wvh = (u16*)(ws + 103022592);        // 1,179,648 B
  u16* XtXp = (u16*)(ws + 104202240);       // 32 z x 21 tiles x 16384 bf16
  u16* XtXbf = (u16*)(ws + 141950976);      // 8 x 589824 bf16
  u16* T = (u16*)(ws + 151388160);          // 8 x 1536 x 768 bf16
  u16* WeffT = (u16*)(ws + 151388160);      // alias: T dead after k_score
  u16* WcompT = (u16*)(ws + 160825344);
  float* Aattn = (float*)(ws + 170262528);  // 64 x 9216 f32
  // total ws use: 172,621,824 B

  // 1. x -> Xh + XhT
  k_cvtT<<<dim3(64, 12, 8), 256, 0, stream>>>(x, Xh, XhT);
  // 2. Wqkv -> Wt + Wvh
  k_wt<<<dim3(72, 24), 256, 0, stream>>>(Wqkv, Wt, Wvh);
  // 3. XtX triangle partials: per (b,s), 21 tile-pairs
  k_gemm<0, 1><<<dim3(21, 1, 32), 256, 0, stream>>>(
      XhT, XhT, (void*)XtXp, nullptr, 1024, 4096, 4096, 0,
      3145728L, 3145728L, 344064L, 4, 1024L);
  // 4. reduce + mirror -> XtXbf (full square)
  k_red<<<dim3(36, 8), 256, 0, stream>>>(XtXp, XtXbf);
  // 5. T[b] = Wt @ XtXbf_b (symmetric -> Bt=XtX)
  k_gemm<0, 0><<<dim3(6, 12, 8), 256, 0, stream>>>(
      Wt, XtXbf, (void*)T, nullptr, 768, 768, 768, 768,
      0L, 589824L, 1179648L, 1, 0L);
  // 6. scores + softmax -> Aattn
  k_score<<<dim3(8, 8), 256, 0, stream>>>(T, Wt, temp, Aattn);
  // 7. WeffT = blockdiag(A)^T @ Wproj
  k_weff<<<dim3(6, 8, 8), 256, 0, stream>>>(Aattn, Wproj, WeffT);
  // 8. WcompT[b][j][k] = sum_e WeffT[b][j][e] * Wvh[k][e]
  k_gemm<0, 0><<<dim3(6, 6, 8), 256, 0, stream>>>(
      WeffT, Wvh, (void*)WcompT, nullptr, 768, 768, 768, 768,
      589824L, 0L, 589824L, 1, 0L);
  // 9. out = Xh_b @ Wcomp_b + bproj (f32 out) -- 256x128 8-wave kernel
  k_gemm2<1><<<dim3(6, 16, 8), 512, 0, stream>>>(
      Xh, WcompT, out, bproj, 768, 768, 768, 768,
      3145728L, 589824L, 3145728L);
}